// Round 9
// baseline (49.953 us; speedup 1.0000x reference)
//
#include <hip/hip_runtime.h>
#include <math.h>

// Problem constants (fixed by the reference): B=4, S=4096, C=2048, K=4
#define BB 4
#define SS 4096
#define CC 2048
#define KK 4

constexpr int TS      = 16;              // timesteps per block strip
constexpr int THREADS = 128;             // threads per block (2 waves)
constexpr int CGRP    = THREADS * 4;     // channels covered per block (float4/thread)
constexpr int CBLK    = CC / CGRP;       // 4 channel-blocks
constexpr int SBLK    = SS / TS;         // 256 strips

typedef float floatx4 __attribute__((ext_vector_type(4)));  // native vec for NT store

__device__ __forceinline__ float silu_fast(float v) {
    // v * 1/(1+exp(-v)); rcpf is ~1ulp approx — output threshold is bf16-level.
    return v * __builtin_amdgcn_rcpf(1.0f + __expf(-v));
}

__global__ __launch_bounds__(THREADS, 8) void causal_conv_kernel(
    const float* __restrict__ x,     // (B,S,C)
    const float* __restrict__ mask,  // (B,S)
    const float* __restrict__ W,     // (C,1,K) -> W[c*K + k]
    const float* __restrict__ bias,  // (C,)
    float* __restrict__ y,           // (B,S,C)
    float* __restrict__ state)       // (B,C,K)
{
    // No XCD swizzle (A/B vs R5): default round-robin dispatch spreads the
    // concurrent NT-write streams across the full y address range instead of
    // confining each XCD to a 32 MiB window — tests write-channel spreading.
    const int blk = blockIdx.x;
    const int b   = blk / (CBLK * SBLK);
    const int r   = blk % (CBLK * SBLK);
    const int cb  = r % CBLK;
    const int s0  = (r / CBLK) * TS;
    const int c   = cb * CGRP + threadIdx.x * 4;

    // Per-channel taps: W layout is channel-major (C, K); one float4 per channel.
    const float4 w0 = *(const float4*)(W + (size_t)(c + 0) * KK);
    const float4 w1 = *(const float4*)(W + (size_t)(c + 1) * KK);
    const float4 w2 = *(const float4*)(W + (size_t)(c + 2) * KK);
    const float4 w3 = *(const float4*)(W + (size_t)(c + 3) * KK);
    const float4 bv = *(const float4*)(bias + c);

    const float* xb = x + (size_t)b * SS * CC + c;
    float*       yb = y + (size_t)b * SS * CC + c;
    const float* mb = mask + (size_t)b * SS;

    // Sliding window: x[s-3], x[s-2], x[s-1] (mask already applied)
    float4 xm4, xm3, xm2, xm1;
    {
        #define LOADX(sv, dst)                                              \
            if ((sv) < 0) { dst = make_float4(0.f, 0.f, 0.f, 0.f); }        \
            else {                                                          \
                float m_ = mb[(sv)];                                        \
                float4 v_ = *(const float4*)(xb + (size_t)(sv) * CC);       \
                dst = make_float4(v_.x * m_, v_.y * m_, v_.z * m_, v_.w * m_); \
            }
        LOADX(s0 - 3, xm3)
        LOADX(s0 - 2, xm2)
        LOADX(s0 - 1, xm1)
        #undef LOADX
    }

    #pragma unroll 4
    for (int s = s0; s < s0 + TS; ++s) {
        const float m = mb[s];
        float4 xc = *(const float4*)(xb + (size_t)s * CC);
        xc.x *= m; xc.y *= m; xc.z *= m; xc.w *= m;

        float4 acc;
        acc.x = fmaf(w0.x, xm3.x, fmaf(w0.y, xm2.x, fmaf(w0.z, xm1.x, fmaf(w0.w, xc.x, bv.x))));
        acc.y = fmaf(w1.x, xm3.y, fmaf(w1.y, xm2.y, fmaf(w1.z, xm1.y, fmaf(w1.w, xc.y, bv.y))));
        acc.z = fmaf(w2.x, xm3.z, fmaf(w2.y, xm2.z, fmaf(w2.z, xm1.z, fmaf(w2.w, xc.z, bv.z))));
        acc.w = fmaf(w3.x, xm3.w, fmaf(w3.y, xm2.w, fmaf(w3.z, xm1.w, fmaf(w3.w, xc.w, bv.w))));

        floatx4 outv;
        outv.x = silu_fast(acc.x) * m;
        outv.y = silu_fast(acc.y) * m;
        outv.z = silu_fast(acc.z) * m;
        outv.w = silu_fast(acc.w) * m;

        __builtin_nontemporal_store(outv, (floatx4*)(yb + (size_t)s * CC));

        xm4 = xm3; xm3 = xm2; xm2 = xm1; xm1 = xc;
    }

    // Fused input_state: blocks owning the final strip hold x[S-4..S-1]*m in
    // registers now (xm4..xm1). state layout (B,C,K): 4 consecutive float4s
    // per thread = 64B contiguous, coalesced.
    if (s0 == SS - TS) {
        float* st = state + ((size_t)b * CC + c) * KK;
        *(float4*)(st + 0)  = make_float4(xm4.x, xm3.x, xm2.x, xm1.x);
        *(float4*)(st + 4)  = make_float4(xm4.y, xm3.y, xm2.y, xm1.y);
        *(float4*)(st + 8)  = make_float4(xm4.z, xm3.z, xm2.z, xm1.z);
        *(float4*)(st + 12) = make_float4(xm4.w, xm3.w, xm2.w, xm1.w);
    }
}

extern "C" void kernel_launch(void* const* d_in, const int* in_sizes, int n_in,
                              void* d_out, int out_size, void* d_ws, size_t ws_size,
                              hipStream_t stream) {
    const float* x    = (const float*)d_in[0];  // hidden_states (B,S,C)
    const float* mask = (const float*)d_in[1];  // attention_mask (B,S)
    const float* W    = (const float*)d_in[2];  // (C,1,K)
    const float* bias = (const float*)d_in[3];  // (C,)

    float* y     = (float*)d_out;                       // (B,S,C) flat
    float* state = y + (size_t)BB * SS * CC;            // (B,C,K) flat, concatenated

    causal_conv_kernel<<<BB * CBLK * SBLK, THREADS, 0, stream>>>(x, mask, W, bias, y, state);
}

// Round 10
// 48.247 us; speedup vs baseline: 1.0354x; 1.0354x over previous
//
#include <hip/hip_runtime.h>
#include <math.h>

// Problem constants (fixed by the reference): B=4, S=4096, C=2048, K=4
#define BB 4
#define SS 4096
#define CC 2048
#define KK 4

constexpr int TS      = 16;              // timesteps per block strip
constexpr int THREADS = 128;             // threads per block (2 waves)
constexpr int CGRP    = THREADS * 4;     // channels covered per block (float4/thread)
constexpr int CBLK    = CC / CGRP;       // 4 channel-blocks
constexpr int SBLK    = SS / TS;         // 256 strips
constexpr int NCOL    = BB * CBLK;       // 16 (b,channel-block) columns
constexpr int NXCD    = 8;

typedef float floatx4 __attribute__((ext_vector_type(4)));  // native vec for NT store

__device__ __forceinline__ float silu_fast(float v) {
    // v * 1/(1+exp(-v)); rcpf is ~1ulp approx — output threshold is bf16-level.
    return v * __builtin_amdgcn_rcpf(1.0f + __expf(-v));
}

__global__ __launch_bounds__(THREADS, 8) void causal_conv_kernel(
    const float* __restrict__ x,     // (B,S,C)
    const float* __restrict__ mask,  // (B,S)
    const float* __restrict__ W,     // (C,1,K) -> W[c*K + k]
    const float* __restrict__ bias,  // (C,)
    float* __restrict__ y,           // (B,S,C)
    float* __restrict__ state)       // (B,C,K)
{
    // XCD-aware swizzle (A/B-verified +3% vs linear in R9): each
    // (b,channel-block) column's 256 strips live on ONE XCD in strip order,
    // so strip-adjacent halo rows hit that XCD's L2.
    // grid = 4096 = 8 XCD * 512; 512 = 2 columns * 256 strips. Bijective.
    const int xcd   = blockIdx.x % NXCD;
    const int inx   = blockIdx.x / NXCD;             // 0..511, time-ordered on this XCD
    const int col   = xcd * (NCOL / NXCD) + inx / SBLK;  // 2 columns per XCD
    const int strip = inx % SBLK;
    const int b     = col / CBLK;
    const int cb    = col % CBLK;
    const int s0    = strip * TS;
    const int c     = cb * CGRP + threadIdx.x * 4;

    // Per-channel taps: W layout is channel-major (C, K); one float4 per channel.
    const float4 w0 = *(const float4*)(W + (size_t)(c + 0) * KK);
    const float4 w1 = *(const float4*)(W + (size_t)(c + 1) * KK);
    const float4 w2 = *(const float4*)(W + (size_t)(c + 2) * KK);
    const float4 w3 = *(const float4*)(W + (size_t)(c + 3) * KK);
    const float4 bv = *(const float4*)(bias + c);

    const float* xb = x + (size_t)b * SS * CC + c;
    float*       yb = y + (size_t)b * SS * CC + c;
    const float* mb = mask + (size_t)b * SS;

    // Sliding window: x[s-3], x[s-2], x[s-1] (mask already applied)
    float4 xm4, xm3, xm2, xm1;
    {
        #define LOADX(sv, dst)                                              \
            if ((sv) < 0) { dst = make_float4(0.f, 0.f, 0.f, 0.f); }        \
            else {                                                          \
                float m_ = mb[(sv)];                                        \
                float4 v_ = *(const float4*)(xb + (size_t)(sv) * CC);       \
                dst = make_float4(v_.x * m_, v_.y * m_, v_.z * m_, v_.w * m_); \
            }
        LOADX(s0 - 3, xm3)
        LOADX(s0 - 2, xm2)
        LOADX(s0 - 1, xm1)
        #undef LOADX
    }

    #pragma unroll 4
    for (int s = s0; s < s0 + TS; ++s) {
        const float m = mb[s];
        float4 xc = *(const float4*)(xb + (size_t)s * CC);
        xc.x *= m; xc.y *= m; xc.z *= m; xc.w *= m;

        float4 acc;
        acc.x = fmaf(w0.x, xm3.x, fmaf(w0.y, xm2.x, fmaf(w0.z, xm1.x, fmaf(w0.w, xc.x, bv.x))));
        acc.y = fmaf(w1.x, xm3.y, fmaf(w1.y, xm2.y, fmaf(w1.z, xm1.y, fmaf(w1.w, xc.y, bv.y))));
        acc.z = fmaf(w2.x, xm3.z, fmaf(w2.y, xm2.z, fmaf(w2.z, xm1.z, fmaf(w2.w, xc.z, bv.z))));
        acc.w = fmaf(w3.x, xm3.w, fmaf(w3.y, xm2.w, fmaf(w3.z, xm1.w, fmaf(w3.w, xc.w, bv.w))));

        floatx4 outv;
        outv.x = silu_fast(acc.x) * m;
        outv.y = silu_fast(acc.y) * m;
        outv.z = silu_fast(acc.z) * m;
        outv.w = silu_fast(acc.w) * m;

        __builtin_nontemporal_store(outv, (floatx4*)(yb + (size_t)s * CC));

        xm4 = xm3; xm3 = xm2; xm2 = xm1; xm1 = xc;
    }

    // Fused input_state: blocks owning the final strip hold x[S-4..S-1]*m in
    // registers now (xm4..xm1). state layout (B,C,K): 4 consecutive float4s
    // per thread = 64B contiguous, coalesced.
    if (s0 == SS - TS) {
        float* st = state + ((size_t)b * CC + c) * KK;
        *(float4*)(st + 0)  = make_float4(xm4.x, xm3.x, xm2.x, xm1.x);
        *(float4*)(st + 4)  = make_float4(xm4.y, xm3.y, xm2.y, xm1.y);
        *(float4*)(st + 8)  = make_float4(xm4.z, xm3.z, xm2.z, xm1.z);
        *(float4*)(st + 12) = make_float4(xm4.w, xm3.w, xm2.w, xm1.w);
    }
}

extern "C" void kernel_launch(void* const* d_in, const int* in_sizes, int n_in,
                              void* d_out, int out_size, void* d_ws, size_t ws_size,
                              hipStream_t stream) {
    const float* x    = (const float*)d_in[0];  // hidden_states (B,S,C)
    const float* mask = (const float*)d_in[1];  // attention_mask (B,S)
    const float* W    = (const float*)d_in[2];  // (C,1,K)
    const float* bias = (const float*)d_in[3];  // (C,)

    float* y     = (float*)d_out;                       // (B,S,C) flat
    float* state = y + (size_t)BB * SS * CC;            // (B,C,K) flat, concatenated

    causal_conv_kernel<<<BB * CBLK * SBLK, THREADS, 0, stream>>>(x, mask, W, bias, y, state);
}